// Round 10
// baseline (191.415 us; speedup 1.0000x reference)
//
#include <hip/hip_runtime.h>
#include <math.h>

// Problem constants
constexpr int Bb = 256;
constexpr int Ll = 512;
constexpr int Dd = 768;
constexpr int Pp = 30;
constexpr int Kk = 4;
constexpr int LOUT = Kk + Ll;          // 516
constexpr int D4   = Dd / 4;           // 192 float4 per row
constexpr int CHUNKS = 8;              // grid = 8*256 = 2048 blocks
constexpr int ROWS   = Ll / CHUNKS;    // 64 rows per chunk (192 KB per block)
constexpr int TPB    = 256;

typedef float f32x4 __attribute__((ext_vector_type(4)));

// d_out layout (float elements): prompted_embedding, similarity, reduce_sim, idx(as float)
constexpr size_t SIM_OFF = (size_t)Bb * LOUT * Dd;        // 101,449,728
constexpr size_t RS_OFF  = SIM_OFF + (size_t)Bb * Pp;     // +7680
constexpr size_t IDX_OFF = RS_OFF + 1;                    // +1

// d_ws layout (float elements)
constexpr size_t PART_OFF = 0;                            // Bb*CHUNKS*Dd floats (6.3 MB)
constexpr size_t RED_OFF  = (size_t)Bb * CHUNKS * Dd;     // Bb floats
constexpr size_t CNT_OFF  = RED_OFF + Bb;                 // 1 uint counter

#define AT_STOREF(p, v) __hip_atomic_store((p), (v), __ATOMIC_RELAXED, __HIP_MEMORY_SCOPE_AGENT)
#define AT_LOADF(p)     __hip_atomic_load((p), __ATOMIC_RELAXED, __HIP_MEMORY_SCOPE_AGENT)
#define AT_STOREU(p, v) __hip_atomic_store((p), (v), __ATOMIC_RELAXED, __HIP_MEMORY_SCOPE_AGENT)

// ---------------------------------------------------------------------------
// Kernel A: copy + column sums. PLAIN loads (L2 read buffering; no NT-load
// latency exposure) + NT stores (R7/R8 A/B: NT stores worth ~10 us — no L2
// write-allocate thrash). 16-deep load batches, launch_bounds(256,4) = 128
// VGPR, 16 waves/CU, 256 KB/CU in flight. Column class of element
// (t + 64*(p+j)) mod 192 depends only on (p+j)%3.
// Block (0,0) also zeroes the cross-kernel counter used by kernel C.
__global__ __launch_bounds__(TPB, 4)
void copy_mean_kernel(const f32x4* __restrict__ x,
                      f32x4* __restrict__ out,
                      f32x4* __restrict__ part,
                      unsigned* __restrict__ cnt) {
    __shared__ f32x4 cls[4][D4];         // 12 KB, transposed: [wave][col]

    const int c = blockIdx.x;            // chunk
    const int b = blockIdx.y;            // batch
    const int t = threadIdx.x;           // 0..255
    const int m = t >> 6;                // wave id 0..3

    if (c == 0 && b == 0 && t == 0) AT_STOREU(cnt, 0u);   // reset each call

    const f32x4* src = x   + (size_t)(b * Ll + c * ROWS) * D4 + t;
    f32x4*       dst = out + (size_t)(b * LOUT + Kk + c * ROWS) * D4 + t;

    f32x4 acc[3];
    acc[0] = f32x4{0,0,0,0}; acc[1] = f32x4{0,0,0,0}; acc[2] = f32x4{0,0,0,0};

    // 3 outer iters x (16 plain loads, then 16 NT stores). 4096 f32x4 per iter.
#pragma unroll
    for (int p = 0; p < 3; ++p) {
        const size_t o = (size_t)p * 4096;
        f32x4 v[16];
#pragma unroll
        for (int j = 0; j < 16; ++j)
            v[j] = src[o + j * 256];
#pragma unroll
        for (int j = 0; j < 16; ++j) {
            __builtin_nontemporal_store(v[j], dst + o + j * 256);
            acc[(p + j) % 3] += v[j];
        }
    }

    // acc[i] holds column class (t + 64*i) % 192; each wave's 64 threads x 3
    // classes cover all 192 cols exactly once -> conflict-free combine.
    cls[m][t % D4]         = acc[0];
    cls[m][(t + 64) % D4]  = acc[1];
    cls[m][(t + 128) % D4] = acc[2];
    __syncthreads();

    if (t < D4) {
        const f32x4 s = cls[0][t] + cls[1][t] + cls[2][t] + cls[3][t];
        part[(size_t)(b * CHUNKS + c) * D4 + t] = s;   // plain cached store
    }
}

// ---------------------------------------------------------------------------
// Kernel C: per-batch tail + folded reduce_sim. 256 blocks x 256.
// red[] handoff rides agent-scope atomics (256 scalars only — the pattern
// that was correct in R6; its cost there was the 6 MB bulk data, not the
// discipline). Last block (ACQ_REL election) computes reduce_sim in fixed
// order -> bit-deterministic.
__global__ void sim_topk_kernel(const float* __restrict__ part,
                                const float* __restrict__ prompt,
                                float* __restrict__ out,
                                float* __restrict__ red,
                                unsigned* __restrict__ cnt) {
    __shared__ float  xn[Dd];
    __shared__ float  sims[Pp];
    __shared__ int    tidx[Kk];
    __shared__ double smem[4];
    __shared__ int    allFlag;

    const int b = blockIdx.x;
    const int t = threadIdx.x;

    // combine chunk partials (double), mean, sum of squares: t<192, 4 floats
    double md[4];
    double ssl = 0.0;
    if (t < D4) {
#pragma unroll
        for (int k = 0; k < 4; ++k) {
            double s = 0.0;
#pragma unroll
            for (int cc = 0; cc < CHUNKS; ++cc)
                s += (double)part[(size_t)(b * CHUNKS + cc) * Dd + 4 * t + k];
            md[k] = s * (1.0 / Ll);
            ssl += md[k] * md[k];
        }
    }
    for (int off = 32; off > 0; off >>= 1) ssl += __shfl_down(ssl, off, 64);
    if ((t & 63) == 0) smem[t >> 6] = ssl;
    __syncthreads();
    const double rs = 1.0 / sqrt(fmax(smem[0] + smem[1] + smem[2] + smem[3], 1e-12));
    if (t < D4) {
#pragma unroll
        for (int k = 0; k < 4; ++k)
            xn[4 * t + k] = (float)(md[k] * rs);
    }
    __syncthreads();

    // similarity with fused prompt normalization: 8 lanes per prompt
    if (t < Pp * 8) {
        const int p = t >> 3;
        const int g = t & 7;
        double dot = 0.0, pss = 0.0;
        for (int i = g; i < Dd; i += 8) {
            const double pv = (double)prompt[p * Dd + i];
            dot += (double)xn[i] * pv;
            pss += pv * pv;
        }
#pragma unroll
        for (int off = 4; off > 0; off >>= 1) {
            dot += __shfl_down(dot, off, 8);
            pss += __shfl_down(pss, off, 8);
        }
        if (g == 0) {
            const float sv = (float)(dot / sqrt(fmax(pss, 1e-12)));
            sims[p] = sv;
            out[SIM_OFF + (size_t)b * Pp + p] = sv;
        }
    }
    __syncthreads();

    // top-4 (strict > keeps earliest index on ties, matching lax.top_k)
    if (t == 0) {
        float sv[Pp];
        for (int p = 0; p < Pp; ++p) sv[p] = sims[p];
        double rsum = 0.0;
        for (int k = 0; k < Kk; ++k) {
            float best = -INFINITY;
            int   bi   = 0;
            for (int p = 0; p < Pp; ++p)
                if (sv[p] > best) { best = sv[p]; bi = p; }
            tidx[k] = bi;
            out[IDX_OFF + (size_t)b * Kk + k] = (float)bi;
            rsum += (double)best;
            sv[bi] = -INFINITY;
        }
        AT_STOREF(red + b, (float)rsum);   // coherent publish (1 dword)
    }
    __syncthreads();

    // batched_prompt: out[b, k, :] = prompt[tidx[k], :]  (768 f32x4 = 256*3)
    {
        const f32x4* pr4 = (const f32x4*)prompt;
        f32x4*       o4  = (f32x4*)out;
#pragma unroll
        for (int jj = 0; jj < 3; ++jj) {
            const int j   = t + 256 * jj;
            const int k   = j / D4;
            const int col = j % D4;
            o4[(size_t)(b * LOUT + k) * D4 + col] = pr4[(size_t)tidx[k] * D4 + col];
        }
    }

    // last-block election: ACQ_REL orders the red[] atomics across XCDs
    if (t == 0)
        allFlag = (__hip_atomic_fetch_add(cnt, 1u, __ATOMIC_ACQ_REL,
                                          __HIP_MEMORY_SCOPE_AGENT) == Bb - 1);
    __syncthreads();
    if (!allFlag) return;

    // reduce_sim, fixed order (bit-deterministic)
    if (t < 64) {
        double v = 0.0;
#pragma unroll
        for (int i = 0; i < 4; ++i)
            v += (double)AT_LOADF(red + t + 64 * i);
        for (int off = 32; off > 0; off >>= 1) v += __shfl_down(v, off, 64);
        if (t == 0) out[RS_OFF] = (float)(v * (1.0 / Bb));
    }
}

// ---------------------------------------------------------------------------
extern "C" void kernel_launch(void* const* d_in, const int* in_sizes, int n_in,
                              void* d_out, int out_size, void* d_ws, size_t ws_size,
                              hipStream_t stream) {
    const float* x_embed = (const float*)d_in[0];   // [256,512,768]
    const float* prompt  = (const float*)d_in[1];   // [30,768]
    float* out = (float*)d_out;
    float* ws  = (float*)d_ws;

    float*    part = ws + PART_OFF;
    float*    red  = ws + RED_OFF;
    unsigned* cnt  = (unsigned*)(ws + CNT_OFF);

    copy_mean_kernel<<<dim3(CHUNKS, Bb), TPB, 0, stream>>>(
        (const f32x4*)x_embed, (f32x4*)out, (f32x4*)part, cnt);

    sim_topk_kernel<<<Bb, TPB, 0, stream>>>(part, prompt, out, red, cnt);
}

// Round 11
// 178.372 us; speedup vs baseline: 1.0731x; 1.0731x over previous
//
#include <hip/hip_runtime.h>
#include <math.h>

// Problem constants
constexpr int Bb = 256;
constexpr int Ll = 512;
constexpr int Dd = 768;
constexpr int Pp = 30;
constexpr int Kk = 4;
constexpr int LOUT = Kk + Ll;          // 516
constexpr int D4   = Dd / 4;           // 192 float4 per row
constexpr int CHUNKS = 8;              // grid = 8*256 = 2048 blocks
constexpr int ROWS   = Ll / CHUNKS;    // 64 rows per chunk (192 KB per block)
constexpr int TPB    = 256;

typedef float f32x4 __attribute__((ext_vector_type(4)));

// d_out layout (float elements): prompted_embedding, similarity, reduce_sim, idx(as float)
constexpr size_t SIM_OFF = (size_t)Bb * LOUT * Dd;        // 101,449,728
constexpr size_t RS_OFF  = SIM_OFF + (size_t)Bb * Pp;     // +7680
constexpr size_t IDX_OFF = RS_OFF + 1;                    // +1

// d_ws layout (float elements)
constexpr size_t PART_OFF = 0;                            // Bb*CHUNKS*Dd floats (6.3 MB)
constexpr size_t RED_OFF  = (size_t)Bb * CHUNKS * Dd;     // Bb floats
constexpr size_t CNT_OFF  = RED_OFF + Bb;                 // 1 uint counter

#define AT_STOREF(p, v) __hip_atomic_store((p), (v), __ATOMIC_RELAXED, __HIP_MEMORY_SCOPE_AGENT)
#define AT_LOADF(p)     __hip_atomic_load((p), __ATOMIC_RELAXED, __HIP_MEMORY_SCOPE_AGENT)
#define AT_STOREU(p, v) __hip_atomic_store((p), (v), __ATOMIC_RELAXED, __HIP_MEMORY_SCOPE_AGENT)

// ---------------------------------------------------------------------------
// Kernel A: copy + column sums. NT loads AND NT stores (mode ledger:
// NT/NT 157us copy; plain loads +20us (R10), plain stores +10us (R8) — any
// L2 involvement loses on this pure streaming pattern). 16-deep load
// batches, launch_bounds(256,4) = 128 VGPR, 16 waves/CU, 256 KB/CU in
// flight. Column class of element (t + 64*(p+j)) mod 192 = (p+j)%3.
// Block (0,0) zeroes the cross-kernel counter used by kernel C's election.
__global__ __launch_bounds__(TPB, 4)
void copy_mean_kernel(const f32x4* __restrict__ x,
                      f32x4* __restrict__ out,
                      f32x4* __restrict__ part,
                      unsigned* __restrict__ cnt) {
    __shared__ f32x4 cls[4][D4];         // 12 KB, transposed: [wave][col]

    const int c = blockIdx.x;            // chunk
    const int b = blockIdx.y;            // batch
    const int t = threadIdx.x;           // 0..255
    const int m = t >> 6;                // wave id 0..3

    if (c == 0 && b == 0 && t == 0) AT_STOREU(cnt, 0u);   // reset each call

    const f32x4* src = x   + (size_t)(b * Ll + c * ROWS) * D4 + t;
    f32x4*       dst = out + (size_t)(b * LOUT + Kk + c * ROWS) * D4 + t;

    f32x4 acc[3];
    acc[0] = f32x4{0,0,0,0}; acc[1] = f32x4{0,0,0,0}; acc[2] = f32x4{0,0,0,0};

    // 3 outer iters x (16 NT loads, then 16 NT stores). 4096 f32x4 per iter.
#pragma unroll
    for (int p = 0; p < 3; ++p) {
        const size_t o = (size_t)p * 4096;
        f32x4 v[16];
#pragma unroll
        for (int j = 0; j < 16; ++j)
            v[j] = __builtin_nontemporal_load(src + o + j * 256);
#pragma unroll
        for (int j = 0; j < 16; ++j) {
            __builtin_nontemporal_store(v[j], dst + o + j * 256);
            acc[(p + j) % 3] += v[j];
        }
    }

    // acc[i] holds column class (t + 64*i) % 192; each wave's 64 threads x 3
    // classes cover all 192 cols exactly once -> conflict-free combine.
    cls[m][t % D4]         = acc[0];
    cls[m][(t + 64) % D4]  = acc[1];
    cls[m][(t + 128) % D4] = acc[2];
    __syncthreads();

    if (t < D4) {
        const f32x4 s = cls[0][t] + cls[1][t] + cls[2][t] + cls[3][t];
        part[(size_t)(b * CHUNKS + c) * D4 + t] = s;   // plain cached store
    }
}

// ---------------------------------------------------------------------------
// Kernel C: per-batch tail + folded reduce_sim. 256 blocks x 256.
// red[] handoff rides agent-scope atomics (256 scalars only; the bulk-data
// version of this was the R6 disaster — volume, not discipline, was the
// cost). Last block (ACQ_REL election) does the fixed-order final sum.
__global__ void sim_topk_kernel(const float* __restrict__ part,
                                const float* __restrict__ prompt,
                                float* __restrict__ out,
                                float* __restrict__ red,
                                unsigned* __restrict__ cnt) {
    __shared__ float  xn[Dd];
    __shared__ float  sims[Pp];
    __shared__ int    tidx[Kk];
    __shared__ double smem[4];
    __shared__ int    allFlag;

    const int b = blockIdx.x;
    const int t = threadIdx.x;

    // combine chunk partials (double), mean, sum of squares: t<192, 4 floats
    double md[4];
    double ssl = 0.0;
    if (t < D4) {
#pragma unroll
        for (int k = 0; k < 4; ++k) {
            double s = 0.0;
#pragma unroll
            for (int cc = 0; cc < CHUNKS; ++cc)
                s += (double)part[(size_t)(b * CHUNKS + cc) * Dd + 4 * t + k];
            md[k] = s * (1.0 / Ll);
            ssl += md[k] * md[k];
        }
    }
    for (int off = 32; off > 0; off >>= 1) ssl += __shfl_down(ssl, off, 64);
    if ((t & 63) == 0) smem[t >> 6] = ssl;
    __syncthreads();
    const double rs = 1.0 / sqrt(fmax(smem[0] + smem[1] + smem[2] + smem[3], 1e-12));
    if (t < D4) {
#pragma unroll
        for (int k = 0; k < 4; ++k)
            xn[4 * t + k] = (float)(md[k] * rs);
    }
    __syncthreads();

    // similarity with fused prompt normalization: 8 lanes per prompt
    if (t < Pp * 8) {
        const int p = t >> 3;
        const int g = t & 7;
        double dot = 0.0, pss = 0.0;
        for (int i = g; i < Dd; i += 8) {
            const double pv = (double)prompt[p * Dd + i];
            dot += (double)xn[i] * pv;
            pss += pv * pv;
        }
#pragma unroll
        for (int off = 4; off > 0; off >>= 1) {
            dot += __shfl_down(dot, off, 8);
            pss += __shfl_down(pss, off, 8);
        }
        if (g == 0) {
            const float sv = (float)(dot / sqrt(fmax(pss, 1e-12)));
            sims[p] = sv;
            out[SIM_OFF + (size_t)b * Pp + p] = sv;
        }
    }
    __syncthreads();

    // top-4 (strict > keeps earliest index on ties, matching lax.top_k)
    if (t == 0) {
        float sv[Pp];
        for (int p = 0; p < Pp; ++p) sv[p] = sims[p];
        double rsum = 0.0;
        for (int k = 0; k < Kk; ++k) {
            float best = -INFINITY;
            int   bi   = 0;
            for (int p = 0; p < Pp; ++p)
                if (sv[p] > best) { best = sv[p]; bi = p; }
            tidx[k] = bi;
            out[IDX_OFF + (size_t)b * Kk + k] = (float)bi;
            rsum += (double)best;
            sv[bi] = -INFINITY;
        }
        AT_STOREF(red + b, (float)rsum);   // coherent publish (1 dword)
    }
    __syncthreads();

    // batched_prompt: out[b, k, :] = prompt[tidx[k], :]  (768 f32x4 = 256*3)
    {
        const f32x4* pr4 = (const f32x4*)prompt;
        f32x4*       o4  = (f32x4*)out;
#pragma unroll
        for (int jj = 0; jj < 3; ++jj) {
            const int j   = t + 256 * jj;
            const int k   = j / D4;
            const int col = j % D4;
            o4[(size_t)(b * LOUT + k) * D4 + col] = pr4[(size_t)tidx[k] * D4 + col];
        }
    }

    // last-block election: ACQ_REL orders the red[] atomics across XCDs
    if (t == 0)
        allFlag = (__hip_atomic_fetch_add(cnt, 1u, __ATOMIC_ACQ_REL,
                                          __HIP_MEMORY_SCOPE_AGENT) == Bb - 1);
    __syncthreads();
    if (!allFlag) return;

    // reduce_sim, fixed order (bit-deterministic)
    if (t < 64) {
        double v = 0.0;
#pragma unroll
        for (int i = 0; i < 4; ++i)
            v += (double)AT_LOADF(red + t + 64 * i);
        for (int off = 32; off > 0; off >>= 1) v += __shfl_down(v, off, 64);
        if (t == 0) out[RS_OFF] = (float)(v * (1.0 / Bb));
    }
}

// ---------------------------------------------------------------------------
extern "C" void kernel_launch(void* const* d_in, const int* in_sizes, int n_in,
                              void* d_out, int out_size, void* d_ws, size_t ws_size,
                              hipStream_t stream) {
    const float* x_embed = (const float*)d_in[0];   // [256,512,768]
    const float* prompt  = (const float*)d_in[1];   // [30,768]
    float* out = (float*)d_out;
    float* ws  = (float*)d_ws;

    float*    part = ws + PART_OFF;
    float*    red  = ws + RED_OFF;
    unsigned* cnt  = (unsigned*)(ws + CNT_OFF);

    copy_mean_kernel<<<dim3(CHUNKS, Bb), TPB, 0, stream>>>(
        (const f32x4*)x_embed, (f32x4*)out, (f32x4*)part, cnt);

    sim_topk_kernel<<<Bb, TPB, 0, stream>>>(part, prompt, out, red, cnt);
}

// Round 12
// 174.847 us; speedup vs baseline: 1.0948x; 1.0202x over previous
//
#include <hip/hip_runtime.h>
#include <math.h>

// Problem constants
constexpr int Bb = 256;
constexpr int Ll = 512;
constexpr int Dd = 768;
constexpr int Pp = 30;
constexpr int Kk = 4;
constexpr int LOUT = Kk + Ll;          // 516
constexpr int D4   = Dd / 4;           // 192 float4 per row
constexpr int CHUNKS = 8;              // grid = 8*256 = 2048 blocks
constexpr int ROWS   = Ll / CHUNKS;    // 64 rows per chunk (192 KB per block)
constexpr int TPB    = 256;

typedef float f32x4 __attribute__((ext_vector_type(4)));

// d_out layout (float elements): prompted_embedding, similarity, reduce_sim, idx(as float)
constexpr size_t SIM_OFF = (size_t)Bb * LOUT * Dd;        // 101,449,728
constexpr size_t RS_OFF  = SIM_OFF + (size_t)Bb * Pp;     // +7680
constexpr size_t IDX_OFF = RS_OFF + 1;                    // +1

// d_ws layout (float elements)
constexpr size_t PART_OFF = 0;                            // Bb*CHUNKS*Dd floats (6.3 MB)
constexpr size_t RED_OFF  = (size_t)Bb * CHUNKS * Dd;     // Bb floats

// ---------------------------------------------------------------------------
// Kernel A: copy + column sums. NT loads AND NT stores (mode ledger:
// NT/NT 157us copy; plain loads +20us (R10), plain stores +10us (R8) — any
// L2 involvement loses on this pure streaming pattern). 16-deep load
// batches, launch_bounds(256,4) = 128 VGPR, 16 waves/CU, 256 KB/CU in
// flight. Column class of element (t + 64*(p+j)) mod 192 = (p+j)%3.
// Cross-kernel handoff via dispatch boundary ONLY — R6/R11 proved any
// agent-scope coherence traffic (bulk data OR scalar elections) loses to
// a kernel boundary on this chip.
__global__ __launch_bounds__(TPB, 4)
void copy_mean_kernel(const f32x4* __restrict__ x,
                      f32x4* __restrict__ out,
                      f32x4* __restrict__ part) {
    __shared__ f32x4 cls[4][D4];         // 12 KB, transposed: [wave][col]

    const int c = blockIdx.x;            // chunk
    const int b = blockIdx.y;            // batch
    const int t = threadIdx.x;           // 0..255
    const int m = t >> 6;                // wave id 0..3

    const f32x4* src = x   + (size_t)(b * Ll + c * ROWS) * D4 + t;
    f32x4*       dst = out + (size_t)(b * LOUT + Kk + c * ROWS) * D4 + t;

    f32x4 acc[3];
    acc[0] = f32x4{0,0,0,0}; acc[1] = f32x4{0,0,0,0}; acc[2] = f32x4{0,0,0,0};

    // 3 outer iters x (16 NT loads, then 16 NT stores). 4096 f32x4 per iter.
#pragma unroll
    for (int p = 0; p < 3; ++p) {
        const size_t o = (size_t)p * 4096;
        f32x4 v[16];
#pragma unroll
        for (int j = 0; j < 16; ++j)
            v[j] = __builtin_nontemporal_load(src + o + j * 256);
#pragma unroll
        for (int j = 0; j < 16; ++j) {
            __builtin_nontemporal_store(v[j], dst + o + j * 256);
            acc[(p + j) % 3] += v[j];
        }
    }

    // acc[i] holds column class (t + 64*i) % 192; each wave's 64 threads x 3
    // classes cover all 192 cols exactly once -> conflict-free combine.
    cls[m][t % D4]         = acc[0];
    cls[m][(t + 64) % D4]  = acc[1];
    cls[m][(t + 128) % D4] = acc[2];
    __syncthreads();

    if (t < D4) {
        const f32x4 s = cls[0][t] + cls[1][t] + cls[2][t] + cls[3][t];
        part[(size_t)(b * CHUNKS + c) * D4 + t] = s;   // plain cached store
    }
}

// ---------------------------------------------------------------------------
// Kernel C: per-batch tail. 256 blocks x 256.
__global__ void sim_topk_kernel(const float* __restrict__ part,
                                const float* __restrict__ prompt,
                                float* __restrict__ out,
                                float* __restrict__ red) {
    __shared__ float  xn[Dd];
    __shared__ float  sims[Pp];
    __shared__ int    tidx[Kk];
    __shared__ double smem[4];

    const int b = blockIdx.x;
    const int t = threadIdx.x;

    // combine chunk partials (double), mean, sum of squares: t<192, 4 floats
    double md[4];
    double ssl = 0.0;
    if (t < D4) {
#pragma unroll
        for (int k = 0; k < 4; ++k) {
            double s = 0.0;
#pragma unroll
            for (int cc = 0; cc < CHUNKS; ++cc)
                s += (double)part[(size_t)(b * CHUNKS + cc) * Dd + 4 * t + k];
            md[k] = s * (1.0 / Ll);
            ssl += md[k] * md[k];
        }
    }
    for (int off = 32; off > 0; off >>= 1) ssl += __shfl_down(ssl, off, 64);
    if ((t & 63) == 0) smem[t >> 6] = ssl;
    __syncthreads();
    const double rs = 1.0 / sqrt(fmax(smem[0] + smem[1] + smem[2] + smem[3], 1e-12));
    if (t < D4) {
#pragma unroll
        for (int k = 0; k < 4; ++k)
            xn[4 * t + k] = (float)(md[k] * rs);
    }
    __syncthreads();

    // similarity with fused prompt normalization: 8 lanes per prompt
    if (t < Pp * 8) {
        const int p = t >> 3;
        const int g = t & 7;
        double dot = 0.0, pss = 0.0;
        for (int i = g; i < Dd; i += 8) {
            const double pv = (double)prompt[p * Dd + i];
            dot += (double)xn[i] * pv;
            pss += pv * pv;
        }
#pragma unroll
        for (int off = 4; off > 0; off >>= 1) {
            dot += __shfl_down(dot, off, 8);
            pss += __shfl_down(pss, off, 8);
        }
        if (g == 0) {
            const float sv = (float)(dot / sqrt(fmax(pss, 1e-12)));
            sims[p] = sv;
            out[SIM_OFF + (size_t)b * Pp + p] = sv;
        }
    }
    __syncthreads();

    // top-4 (strict > keeps earliest index on ties, matching lax.top_k)
    if (t == 0) {
        float sv[Pp];
        for (int p = 0; p < Pp; ++p) sv[p] = sims[p];
        double rsum = 0.0;
        for (int k = 0; k < Kk; ++k) {
            float best = -INFINITY;
            int   bi   = 0;
            for (int p = 0; p < Pp; ++p)
                if (sv[p] > best) { best = sv[p]; bi = p; }
            tidx[k] = bi;
            out[IDX_OFF + (size_t)b * Kk + k] = (float)bi;
            rsum += (double)best;
            sv[bi] = -INFINITY;
        }
        red[b] = (float)rsum;
    }
    __syncthreads();

    // batched_prompt: out[b, k, :] = prompt[tidx[k], :]  (768 f32x4 = 256*3)
    {
        const f32x4* pr4 = (const f32x4*)prompt;
        f32x4*       o4  = (f32x4*)out;
#pragma unroll
        for (int jj = 0; jj < 3; ++jj) {
            const int j   = t + 256 * jj;
            const int k   = j / D4;
            const int col = j % D4;
            o4[(size_t)(b * LOUT + k) * D4 + col] = pr4[(size_t)tidx[k] * D4 + col];
        }
    }
}

// ---------------------------------------------------------------------------
// Kernel D: reduce_sim = sum_b red[b] / B. 1 block x 256.
__global__ void finalize_kernel(const float* __restrict__ red,
                                float* __restrict__ out) {
    __shared__ double smem[4];
    const int t = threadIdx.x;
    double v = (double)red[t];
    for (int off = 32; off > 0; off >>= 1) v += __shfl_down(v, off, 64);
    if ((t & 63) == 0) smem[t >> 6] = v;
    __syncthreads();
    if (t == 0)
        out[RS_OFF] = (float)((smem[0] + smem[1] + smem[2] + smem[3]) * (1.0 / Bb));
}

// ---------------------------------------------------------------------------
extern "C" void kernel_launch(void* const* d_in, const int* in_sizes, int n_in,
                              void* d_out, int out_size, void* d_ws, size_t ws_size,
                              hipStream_t stream) {
    const float* x_embed = (const float*)d_in[0];   // [256,512,768]
    const float* prompt  = (const float*)d_in[1];   // [30,768]
    float* out = (float*)d_out;
    float* ws  = (float*)d_ws;

    float* part = ws + PART_OFF;
    float* red  = ws + RED_OFF;

    copy_mean_kernel<<<dim3(CHUNKS, Bb), TPB, 0, stream>>>(
        (const f32x4*)x_embed, (f32x4*)out, (f32x4*)part);

    sim_topk_kernel<<<Bb, TPB, 0, stream>>>(part, prompt, out, red);

    finalize_kernel<<<1, Bb, 0, stream>>>(red, out);
}